// Round 2
// baseline (6361.182 us; speedup 1.0000x reference)
//
#include <hip/hip_runtime.h>

// ---------- bf16 helpers for INTERMEDIATE storage (inputs/outputs are fp32) ----------
__device__ __forceinline__ float b2f(unsigned short u){
  union { unsigned int i; float f; } z; z.i = ((unsigned int)u) << 16; return z.f;
}
__device__ __forceinline__ unsigned short f2b(float f){
  union { float f; unsigned int i; } z; z.f = f;
  unsigned int lsb = (z.i >> 16) & 1u;
  return (unsigned short)((z.i + 0x7fffu + lsb) >> 16);
}

#define EPSf 1e-5f

// ---------------------------------------------------------------------------
// K0a: fold BN1/BN2 into 3x3 weights (1x1 folded into center tap) + bias
// ---------------------------------------------------------------------------
__global__ __launch_bounds__(256) void k_prep_w3(
    const float* __restrict__ w1, const float* __restrict__ w2,
    const float* __restrict__ g1, const float* __restrict__ b1,
    const float* __restrict__ m1, const float* __restrict__ v1,
    const float* __restrict__ g2, const float* __restrict__ b2,
    const float* __restrict__ m2, const float* __restrict__ v2,
    float* __restrict__ W3, float* __restrict__ BIASL){
  int e = blockIdx.x*256 + threadIdx.x;       // < 589824
  int c = e / 2304; int r = e - c*2304; int s = r / 9; int t = r - s*9;
  float inv1 = g1[c] * rsqrtf(v1[c] + EPSf);
  float val = w1[e] * inv1;
  if (t == 4){
    float inv2 = g2[c] * rsqrtf(v2[c] + EPSf);
    val += w2[c*256 + s] * inv2;
  }
  W3[e] = val;
  if (e < 256){
    float i1 = g1[e] * rsqrtf(v1[e] + EPSf);
    float i2 = g2[e] * rsqrtf(v2[e] + EPSf);
    BIASL[e] = (b1[e] - m1[e]*i1) + (b2[e] - m2[e]*i2);
  }
}

// ---------------------------------------------------------------------------
// K0b: fold BNp into pointwise weights
// ---------------------------------------------------------------------------
__global__ __launch_bounds__(256) void k_prep_pw(
    const float* __restrict__ wpw,
    const float* __restrict__ gp, const float* __restrict__ bp,
    const float* __restrict__ mp, const float* __restrict__ vp,
    float* __restrict__ WPW, float* __restrict__ BIASPW){
  __shared__ float invp[256], betap[256];
  int t = threadIdx.x;
  float iv = gp[t] * rsqrtf(vp[t] + EPSf);
  invp[t] = iv; betap[t] = bp[t] - mp[t]*iv;
  __syncthreads();
  float bias = 0.f;
  for (int c = 0; c < 256; ++c){
    float w = wpw[t*256 + c];
    WPW[t*256 + c] = w * invp[c];
    bias += w * betap[c];
  }
  BIASPW[t] = bias;
}

// ---------------------------------------------------------------------------
// K1: local = conv3x3(y, W3) + BIASL  -> LOCB (bf16)
// ---------------------------------------------------------------------------
__global__ __launch_bounds__(256) void k_local(
    const float* __restrict__ y, const float* __restrict__ W3,
    const float* __restrict__ BIASL, unsigned short* __restrict__ LOCB){
  __shared__ float yt[8][3][68];
  __shared__ float wt[72][64];
  int bi = blockIdx.x;
  int ct = bi & 3, wsg = (bi>>2)&3, h = (bi>>4)&255, b = bi>>12;
  int c0 = ct<<6, w0 = wsg<<6;
  int t = threadIdx.x;
  int p = t & 63, cg16 = (t >> 6) << 4;
  float acc[16];
  #pragma unroll
  for (int i=0;i<16;++i) acc[i]=0.f;
  for (int s0 = 0; s0 < 256; s0 += 8){
    for (int e = t; e < 1584; e += 256){
      int sl = e / 198; int r2 = e - sl*198; int rl = r2 / 66; int col = r2 - rl*66;
      int gh = h - 1 + rl; int gw = w0 - 1 + col;
      float v = 0.f;
      if (((unsigned)gh < 256u) && ((unsigned)gw < 256u))
        v = y[((b*256 + s0 + sl)*256 + gh)*256 + gw];
      yt[sl][rl][col] = v;
    }
    for (int e = t; e < 4608; e += 256){
      int r = e >> 6; int cl = e & 63;
      wt[r][cl] = W3[(c0+cl)*2304 + s0*9 + r];
    }
    __syncthreads();
    #pragma unroll
    for (int sl = 0; sl < 8; ++sl){
      #pragma unroll
      for (int tap = 0; tap < 9; ++tap){
        float yv = yt[sl][tap/3][p + (tap % 3)];
        const float* wr = &wt[sl*9 + tap][cg16];
        float4 wv0 = *(const float4*)(wr);
        float4 wv1 = *(const float4*)(wr+4);
        float4 wv2 = *(const float4*)(wr+8);
        float4 wv3 = *(const float4*)(wr+12);
        acc[0]  += yv*wv0.x; acc[1]  += yv*wv0.y; acc[2]  += yv*wv0.z; acc[3]  += yv*wv0.w;
        acc[4]  += yv*wv1.x; acc[5]  += yv*wv1.y; acc[6]  += yv*wv1.z; acc[7]  += yv*wv1.w;
        acc[8]  += yv*wv2.x; acc[9]  += yv*wv2.y; acc[10] += yv*wv2.z; acc[11] += yv*wv2.w;
        acc[12] += yv*wv3.x; acc[13] += yv*wv3.y; acc[14] += yv*wv3.z; acc[15] += yv*wv3.w;
      }
    }
    __syncthreads();
  }
  int outb = ((b*256 + c0 + cg16)*256 + h)*256 + w0 + p;
  #pragma unroll
  for (int i=0;i<16;++i)
    LOCB[outb + i*65536] = f2b(acc[i] + BIASL[c0 + cg16 + i]);
}

// ---------------------------------------------------------------------------
// K2: fused qkv 1x1 conv + window attention -> ATT (bf16, NCHW)
// ---------------------------------------------------------------------------
__global__ __launch_bounds__(256) void k_attn(
    const float* __restrict__ x, const float* __restrict__ wqkv,
    const float* __restrict__ rpb, unsigned short* __restrict__ ATT){
  __shared__ unsigned short xt[64*264];
  __shared__ float un[4160];
  __shared__ float qk[3*1088];
  int t = threadIdx.x;
  int bi = blockIdx.x;
  int b = bi >> 10; int wi = bi & 1023;
  int h0 = (wi >> 5) << 3; int w0 = (wi & 31) << 3;
  int tok = t & 63, grp = t >> 6;
  for (int e = t; e < 16384; e += 256){
    int c = e >> 6; int tk = e & 63;
    int r = tk >> 3, cc = tk & 7;
    xt[tk*264 + c] = f2b(x[((b*256 + c)*256 + (h0+r))*256 + (w0+cc)]);
  }
  __syncthreads();
  int ri = tok >> 3, ci = tok & 7;
  for (int hd = 0; hd < 16; ++hd){
    for (int mat = 0; mat < 3; ++mat){
      for (int e = t; e < 4096; e += 256){
        int d = e >> 8; int c = e & 255;
        un[d*256 + c] = wqkv[((mat<<8) + (hd<<4) + d)*256 + c];
      }
      __syncthreads();
      float a0=0.f, a1=0.f, a2=0.f, a3=0.f;
      const unsigned short* xrow = &xt[tok*264];
      const float* w0p = &un[grp*256];
      #pragma unroll 8
      for (int c = 0; c < 256; c += 4){
        uint2 xr = *(const uint2*)&xrow[c];
        float x0 = b2f((unsigned short)(xr.x & 0xffffu));
        float x1 = b2f((unsigned short)(xr.x >> 16));
        float x2 = b2f((unsigned short)(xr.y & 0xffffu));
        float x3 = b2f((unsigned short)(xr.y >> 16));
        float4 wa = *(const float4*)(w0p + c);
        float4 wb = *(const float4*)(w0p + 1024 + c);
        float4 wc = *(const float4*)(w0p + 2048 + c);
        float4 wd = *(const float4*)(w0p + 3072 + c);
        a0 += x0*wa.x + x1*wa.y + x2*wa.z + x3*wa.w;
        a1 += x0*wb.x + x1*wb.y + x2*wb.z + x3*wb.w;
        a2 += x0*wc.x + x1*wc.y + x2*wc.z + x3*wc.w;
        a3 += x0*wd.x + x1*wd.y + x2*wd.z + x3*wd.w;
      }
      float s = (mat == 0) ? 0.25f : 1.f;
      float* qkm = &qk[mat*1088 + tok*17];
      qkm[grp] = a0*s; qkm[grp+4] = a1*s; qkm[grp+8] = a2*s; qkm[grp+12] = a3*s;
      __syncthreads();
    }
    float qv[16];
    const float* qrow = &qk[tok*17];
    #pragma unroll
    for (int d = 0; d < 16; ++d) qv[d] = qrow[d];
    float* sm = un;
    #pragma unroll 2
    for (int jj = 0; jj < 16; ++jj){
      int j = (grp<<4) + jj;
      const float* krow = &qk[1088 + j*17];
      float dacc = 0.f;
      #pragma unroll
      for (int d = 0; d < 16; ++d) dacc += qv[d]*krow[d];
      int rj = j >> 3, cj = j & 7;
      int idx = (ri - rj + 7)*15 + (ci - cj + 7);
      sm[tok*65 + j] = dacc + rpb[(idx<<4) + hd];
    }
    __syncthreads();
    if (t < 64){
      float* row = &sm[t*65];
      float mx = -1e30f;
      #pragma unroll 8
      for (int j = 0; j < 64; ++j) mx = fmaxf(mx, row[j]);
      float sum = 0.f;
      #pragma unroll 8
      for (int j = 0; j < 64; ++j){ float e_ = __expf(row[j]-mx); row[j] = e_; sum += e_; }
      float inv = 1.f / sum;
      #pragma unroll 8
      for (int j = 0; j < 64; ++j) row[j] *= inv;
    }
    __syncthreads();
    float o0=0.f,o1=0.f,o2=0.f,o3=0.f;
    const float* arow = &sm[tok*65];
    #pragma unroll 4
    for (int j = 0; j < 64; ++j){
      float a = arow[j];
      const float* vrow = &qk[2176 + j*17];
      o0 += a*vrow[grp]; o1 += a*vrow[grp+4]; o2 += a*vrow[grp+8]; o3 += a*vrow[grp+12];
    }
    int base = ((b*256 + (hd<<4) + grp)*256 + (h0 + ri))*256 + (w0 + ci);
    ATT[base]            = f2b(o0);
    ATT[base + 4*65536]  = f2b(o1);
    ATT[base + 8*65536]  = f2b(o2);
    ATT[base + 12*65536] = f2b(o3);
    __syncthreads();
  }
}

// ---------------------------------------------------------------------------
// K3: comb = avgpool_v(attn) + avgpool_h(attn) + local, in-place into LOCB.
// ---------------------------------------------------------------------------
__global__ __launch_bounds__(256) void k_comb(
    const unsigned short* __restrict__ ATT, unsigned short* __restrict__ LOCB){
  __shared__ float pt[39][256];
  int bi = blockIdx.x;
  int rb = bi & 7; int c = (bi>>3)&255; int b = bi>>11;
  int h0 = rb<<5;
  int t = threadIdx.x;
  const unsigned short* P = ATT + (b*256 + c)*65536;
  for (int e = t; e < 9984; e += 256){
    int r = e >> 8; int cc = e & 255;
    int g = h0 - 3 + r;
    float v = 0.f;
    if ((unsigned)g < 256u) v = b2f(P[(g<<8) + cc]);
    else if (g == 256) v = b2f(P[(254<<8) + cc]);
    pt[r][cc] = v;
  }
  __syncthreads();
  int w = t;
  float colsum = 0.f;
  #pragma unroll
  for (int k = 0; k < 8; ++k) colsum += pt[k][w];
  unsigned short* O = LOCB + (b*256 + c)*65536 + (h0<<8);
  for (int hr = 0; hr < 32; ++hr){
    const float* prow = pt[hr + 3];
    float s = 0.f;
    #pragma unroll
    for (int j = 0; j < 8; ++j){
      int cc = w - 3 + j;
      float v = 0.f;
      if ((unsigned)cc < 256u) v = prow[cc];
      else if (cc == 256) v = prow[254];
      s += v;
    }
    float res = (colsum + s)*0.125f + b2f(O[(hr<<8) + w]);
    O[(hr<<8) + w] = f2b(res);
    if (hr < 31) colsum += pt[hr+8][w] - pt[hr][w];
  }
}

// ---------------------------------------------------------------------------
// K4: 8x8 depthwise conv, reflect(0,1) pad + zero conv-pad 3 -> DWO (bf16)
// ---------------------------------------------------------------------------
__global__ __launch_bounds__(256) void k_dw(
    const unsigned short* __restrict__ COMB, const float* __restrict__ wdw,
    unsigned short* __restrict__ DWO){
  __shared__ float pt[39][264];
  __shared__ float wl[64];
  int bi = blockIdx.x;
  int rb = bi & 7; int c = (bi>>3)&255; int b = bi>>11;
  int h0 = rb<<5;
  int t = threadIdx.x;
  const unsigned short* P = COMB + (b*256 + c)*65536;
  for (int e = t; e < 10296; e += 256){
    int r = e / 264; int cc = e - r*264;
    int g = h0 - 3 + r;
    int gc = cc - 3;
    int gr  = (g  == 256) ? 254 : g;
    int gcc = (gc == 256) ? 254 : gc;
    float v = 0.f;
    if (((unsigned)gr < 256u) && ((unsigned)gcc < 256u))
      v = b2f(P[(gr<<8) + gcc]);
    pt[r][cc] = v;
  }
  if (t < 64) wl[t] = wdw[(c<<6) + t];
  __syncthreads();
  int w = t;
  for (int hr = 0; hr < 32; ++hr){
    float acc = 0.f;
    #pragma unroll
    for (int i = 0; i < 8; ++i){
      const float* prow = &pt[hr + i][w];
      #pragma unroll
      for (int j = 0; j < 8; ++j)
        acc += wl[(i<<3) + j] * prow[j];
    }
    DWO[(b*256 + c)*65536 + ((h0+hr)<<8) + w] = f2b(acc);
  }
}

// ---------------------------------------------------------------------------
// K5: pointwise 1x1 (BNp folded) -> OUT fp32
// ---------------------------------------------------------------------------
__global__ __launch_bounds__(256) void k_pw(
    const unsigned short* __restrict__ DW, const float* __restrict__ WPW,
    const float* __restrict__ BIASPW, float* __restrict__ OUT){
  __shared__ float wt[16][68];
  __shared__ float dt[16][65];
  int bi = blockIdx.x;
  int ot = bi & 3; int ptile = bi >> 2;
  int t = threadIdx.x;
  int p = t & 63, cg16 = (t>>6)<<4;
  int n0 = ptile << 6;
  int b = n0 >> 16; int pix0 = n0 & 65535;
  const unsigned short* Dbase = DW + b*16777216 + pix0;
  float acc[16];
  #pragma unroll
  for (int i=0;i<16;++i) acc[i] = 0.f;
  for (int k0 = 0; k0 < 256; k0 += 16){
    for (int e = t; e < 1024; e += 256){
      int kk = e >> 6; int pp = e & 63;
      dt[kk][pp] = b2f(Dbase[(k0+kk)*65536 + pp]);
    }
    for (int e = t; e < 1024; e += 256){
      int oc_l = e >> 4; int k = e & 15;
      wt[k][oc_l] = WPW[((ot<<6) + oc_l)*256 + k0 + k];
    }
    __syncthreads();
    #pragma unroll
    for (int k = 0; k < 16; ++k){
      float dv = dt[k][p];
      const float* wr = &wt[k][cg16];
      float4 w0v = *(const float4*)(wr);
      float4 w1v = *(const float4*)(wr+4);
      float4 w2v = *(const float4*)(wr+8);
      float4 w3v = *(const float4*)(wr+12);
      acc[0]  += dv*w0v.x; acc[1]  += dv*w0v.y; acc[2]  += dv*w0v.z; acc[3]  += dv*w0v.w;
      acc[4]  += dv*w1v.x; acc[5]  += dv*w1v.y; acc[6]  += dv*w1v.z; acc[7]  += dv*w1v.w;
      acc[8]  += dv*w2v.x; acc[9]  += dv*w2v.y; acc[10] += dv*w2v.z; acc[11] += dv*w2v.w;
      acc[12] += dv*w3v.x; acc[13] += dv*w3v.y; acc[14] += dv*w3v.z; acc[15] += dv*w3v.w;
    }
    __syncthreads();
  }
  int oc0 = (ot<<6) + cg16;
  int ob = b*16777216 + pix0 + p;
  #pragma unroll
  for (int i=0;i<16;++i)
    OUT[ob + (oc0+i)*65536] = acc[i] + BIASPW[oc0+i];
}

// ---------------------------------------------------------------------------
extern "C" void kernel_launch(void* const* d_in, const int* in_sizes, int n_in,
                              void* d_out, int out_size, void* d_ws, size_t ws_size,
                              hipStream_t stream){
  const float* x    = (const float*)d_in[0];
  const float* y    = (const float*)d_in[1];
  const float* wqkv = (const float*)d_in[2];
  const float* wl1  = (const float*)d_in[3];
  const float* g1   = (const float*)d_in[4];
  const float* b1   = (const float*)d_in[5];
  const float* m1   = (const float*)d_in[6];
  const float* v1   = (const float*)d_in[7];
  const float* wl2  = (const float*)d_in[8];
  const float* g2   = (const float*)d_in[9];
  const float* b2   = (const float*)d_in[10];
  const float* m2   = (const float*)d_in[11];
  const float* v2   = (const float*)d_in[12];
  const float* wdw  = (const float*)d_in[13];
  const float* gp   = (const float*)d_in[14];
  const float* bp   = (const float*)d_in[15];
  const float* mp   = (const float*)d_in[16];
  const float* vp   = (const float*)d_in[17];
  const float* wpw  = (const float*)d_in[18];
  const float* rpb  = (const float*)d_in[19];

  float* W3     = (float*)d_ws;                    // 589824 f32
  float* BIASL  = W3 + 589824;                     // 256
  float* WPW    = BIASL + 256;                     // 65536
  float* BIASPW = WPW + 65536;                     // 256
  unsigned short* ATT  = (unsigned short*)(BIASPW + 256);  // 33.5M bf16 (reused as dw_out)
  unsigned short* LOCB = ATT + 33554432;                   // 33.5M bf16 (local -> comb in place)
  float* OUT = (float*)d_out;

  k_prep_w3<<<2304, 256, 0, stream>>>(wl1, wl2, g1, b1, m1, v1, g2, b2, m2, v2, W3, BIASL);
  k_prep_pw<<<1, 256, 0, stream>>>(wpw, gp, bp, mp, vp, WPW, BIASPW);
  k_local<<<8192, 256, 0, stream>>>(y, W3, BIASL, LOCB);
  k_attn<<<2048, 256, 0, stream>>>(x, wqkv, rpb, ATT);
  k_comb<<<4096, 256, 0, stream>>>(ATT, LOCB);
  k_dw<<<4096, 256, 0, stream>>>(LOCB, wdw, ATT);
  k_pw<<<8192, 256, 0, stream>>>(ATT, WPW, BIASPW, OUT);
}

// Round 3
// 3598.618 us; speedup vs baseline: 1.7677x; 1.7677x over previous
//
#include <hip/hip_runtime.h>

typedef unsigned short u16;
typedef __bf16 bf8 __attribute__((ext_vector_type(8)));
typedef float f32x4 __attribute__((ext_vector_type(4)));

// ---------- bf16 helpers for INTERMEDIATE storage (inputs/outputs are fp32) ----------
__device__ __forceinline__ float b2f(u16 u){
  union { unsigned int i; float f; } z; z.i = ((unsigned int)u) << 16; return z.f;
}
__device__ __forceinline__ u16 f2b(float f){
  union { float f; unsigned int i; } z; z.f = f;
  unsigned int lsb = (z.i >> 16) & 1u;
  return (u16)((z.i + 0x7fffu + lsb) >> 16);
}

#define EPSf 1e-5f

// ---------------------------------------------------------------------------
// K0a: fold BN1/BN2 into 3x3 weights (1x1 into center tap) -> W3B bf16 in
// MFMA A-frag layout [ct4][c8 8][tap9][q4][oc64][j8], + BIASL fp32.
// grid 2304 x 256
// ---------------------------------------------------------------------------
__global__ __launch_bounds__(256) void k_prep_w3(
    const float* __restrict__ w1, const float* __restrict__ w2,
    const float* __restrict__ g1, const float* __restrict__ b1,
    const float* __restrict__ m1, const float* __restrict__ v1,
    const float* __restrict__ g2, const float* __restrict__ b2,
    const float* __restrict__ m2, const float* __restrict__ v2,
    u16* __restrict__ W3B, float* __restrict__ BIASL){
  int e = blockIdx.x*256 + threadIdx.x;       // < 589824
  int c = e / 2304; int r = e - c*2304; int s = r / 9; int tap = r - s*9;
  float inv1 = g1[c] * rsqrtf(v1[c] + EPSf);
  float val = w1[e] * inv1;
  if (tap == 4){
    float inv2 = g2[c] * rsqrtf(v2[c] + EPSf);
    val += w2[c*256 + s] * inv2;
  }
  int ct = c >> 6, oc_l = c & 63;
  int c8 = s >> 5, q = (s >> 3) & 3, j = s & 7;
  W3B[((((ct*8 + c8)*9 + tap)*4 + q)*64 + oc_l)*8 + j] = f2b(val);
  if (e < 256){
    float i1 = g1[e] * rsqrtf(v1[e] + EPSf);
    float i2 = g2[e] * rsqrtf(v2[e] + EPSf);
    BIASL[e] = (b1[e] - m1[e]*i1) + (b2[e] - m2[e]*i2);
  }
}

// ---------------------------------------------------------------------------
// K0b: fold BNp into pointwise weights
// ---------------------------------------------------------------------------
__global__ __launch_bounds__(256) void k_prep_pw(
    const float* __restrict__ wpw,
    const float* __restrict__ gp, const float* __restrict__ bp,
    const float* __restrict__ mp, const float* __restrict__ vp,
    float* __restrict__ WPW, float* __restrict__ BIASPW){
  __shared__ float invp[256], betap[256];
  int t = threadIdx.x;
  float iv = gp[t] * rsqrtf(vp[t] + EPSf);
  invp[t] = iv; betap[t] = bp[t] - mp[t]*iv;
  __syncthreads();
  float bias = 0.f;
  for (int c = 0; c < 256; ++c){
    float w = wpw[t*256 + c];
    WPW[t*256 + c] = w * invp[c];
    bias += w * betap[c];
  }
  BIASPW[t] = bias;
}

// ---------------------------------------------------------------------------
// K0c: transpose y (fp32 NCHW) -> YT bf16 NHWC [b][h][w][cin].
// one block per (b,h). grid 512 x 256.
// ---------------------------------------------------------------------------
__global__ __launch_bounds__(256) void k_prep_yT(
    const float* __restrict__ y, u16* __restrict__ YT){
  __shared__ u16 ls[32*264];            // [cin32][w 256(+8)]
  int bh = blockIdx.x; int b = bh >> 8; int h = bh & 255;
  int t = threadIdx.x;
  for (int c8 = 0; c8 < 8; ++c8){
    if (c8) __syncthreads();
    for (int ci = 0; ci < 32; ++ci)
      ls[ci*264 + t] = f2b(y[(b*256 + c8*32 + ci)*65536 + h*256 + t]);
    __syncthreads();
    int tq = t & 3, wl = t >> 2;
    for (int wb = 0; wb < 4; ++wb){
      int w = wb*64 + wl;
      u16 tmp[8];
      #pragma unroll
      for (int j = 0; j < 8; ++j) tmp[j] = ls[(tq*8 + j)*264 + w];
      *(uint4*)(YT + ((b*256 + h)*256 + w)*256 + c8*32 + tq*8) = *(const uint4*)tmp;
    }
  }
}

// ---------------------------------------------------------------------------
// K1: local conv3x3 as implicit GEMM via MFMA 16x16x32 bf16.
// block = 64 oc x 64 px (one output row segment), 4 waves, grid 8192 x 256.
// K loop: 8 cin-chunks x 9 taps. LDS: wt 36864B + yt 16320B = 53184B.
// ---------------------------------------------------------------------------
__global__ __launch_bounds__(256) void k_local(
    const u16* __restrict__ YT, const u16* __restrict__ W3B,
    const float* __restrict__ BIASL, u16* __restrict__ LOCB){
  __shared__ __align__(16) u16 wt[18432];   // [tap9][q4][oc64][j8]
  __shared__ __align__(16) u16 yt[8160];    // [row3][col68 (stride 40)][cin32]
  int bi = blockIdx.x;
  int ct = bi & 3, wsg = (bi>>2)&3, h = (bi>>4)&255, b = bi>>12;
  int w0 = wsg << 6;
  int t = threadIdx.x;
  int wv = t >> 6, lane = t & 63, pxl = lane & 15, quad = lane >> 4;
  f32x4 acc0 = {0.f,0.f,0.f,0.f}, acc1 = acc0, acc2 = acc0, acc3 = acc0;
  const u16* wsrc = W3B + ct*8*18432;
  for (int c8 = 0; c8 < 8; ++c8){
    if (c8) __syncthreads();
    // stage W3B chunk: contiguous 36864 B
    const uint4* gs = (const uint4*)(wsrc + c8*18432);
    uint4* wd = (uint4*)wt;
    #pragma unroll
    for (int i = 0; i < 9; ++i) wd[i*256 + t] = gs[i*256 + t];
    // stage y tile: 3 rows x 66 cols x 32 cin (zero pad OOB)
    for (int e = t; e < 792; e += 256){
      int rc = e >> 2, q = e & 3;
      int row = rc / 66, col = rc - row*66;
      int gh = h - 1 + row, gw = w0 - 1 + col;
      uint4 v = make_uint4(0u,0u,0u,0u);
      if (((unsigned)gh < 256u) && ((unsigned)gw < 256u))
        v = *(const uint4*)(YT + ((b*256 + gh)*256 + gw)*256 + c8*32 + q*8);
      *(uint4*)(yt + (row*68 + col)*40 + q*8) = v;
    }
    __syncthreads();
    #pragma unroll
    for (int tap = 0; tap < 9; ++tap){
      int dr = tap / 3, dc = tap - dr*3;
      bf8 a = *(const bf8*)(wt + ((tap*4 + quad)*64 + wv*16 + pxl)*8);
      int boff = (dr*68 + dc + pxl)*40 + quad*8;
      acc0 = __builtin_amdgcn_mfma_f32_16x16x32_bf16(a, *(const bf8*)(yt + boff       ), acc0, 0,0,0);
      acc1 = __builtin_amdgcn_mfma_f32_16x16x32_bf16(a, *(const bf8*)(yt + boff +  640), acc1, 0,0,0);
      acc2 = __builtin_amdgcn_mfma_f32_16x16x32_bf16(a, *(const bf8*)(yt + boff + 1280), acc2, 0,0,0);
      acc3 = __builtin_amdgcn_mfma_f32_16x16x32_bf16(a, *(const bf8*)(yt + boff + 1920), acc3, 0,0,0);
    }
  }
  int ocb = ct*64 + wv*16 + quad*4;
  float bs[4];
  #pragma unroll
  for (int r = 0; r < 4; ++r) bs[r] = BIASL[ocb + r];
  u16* ob = LOCB + (b*256 + ocb)*65536 + h*256 + w0 + pxl;
  #pragma unroll
  for (int r = 0; r < 4; ++r){
    ob[r*65536 +  0] = f2b(acc0[r] + bs[r]);
    ob[r*65536 + 16] = f2b(acc1[r] + bs[r]);
    ob[r*65536 + 32] = f2b(acc2[r] + bs[r]);
    ob[r*65536 + 48] = f2b(acc3[r] + bs[r]);
  }
}

// ---------------------------------------------------------------------------
// K2: fused qkv 1x1 conv + window attention -> ATT (bf16, NCHW)
// ---------------------------------------------------------------------------
__global__ __launch_bounds__(256) void k_attn(
    const float* __restrict__ x, const float* __restrict__ wqkv,
    const float* __restrict__ rpb, u16* __restrict__ ATT){
  __shared__ u16 xt[64*264];
  __shared__ float un[4160];
  __shared__ float qk[3*1088];
  int t = threadIdx.x;
  int bi = blockIdx.x;
  int b = bi >> 10; int wi = bi & 1023;
  int h0 = (wi >> 5) << 3; int w0 = (wi & 31) << 3;
  int tok = t & 63, grp = t >> 6;
  for (int e = t; e < 16384; e += 256){
    int c = e >> 6; int tk = e & 63;
    int r = tk >> 3, cc = tk & 7;
    xt[tk*264 + c] = f2b(x[((b*256 + c)*256 + (h0+r))*256 + (w0+cc)]);
  }
  __syncthreads();
  int ri = tok >> 3, ci = tok & 7;
  for (int hd = 0; hd < 16; ++hd){
    for (int mat = 0; mat < 3; ++mat){
      for (int e = t; e < 4096; e += 256){
        int d = e >> 8; int c = e & 255;
        un[d*256 + c] = wqkv[((mat<<8) + (hd<<4) + d)*256 + c];
      }
      __syncthreads();
      float a0=0.f, a1=0.f, a2=0.f, a3=0.f;
      const u16* xrow = &xt[tok*264];
      const float* w0p = &un[grp*256];
      #pragma unroll 8
      for (int c = 0; c < 256; c += 4){
        uint2 xr = *(const uint2*)&xrow[c];
        float x0 = b2f((u16)(xr.x & 0xffffu));
        float x1 = b2f((u16)(xr.x >> 16));
        float x2 = b2f((u16)(xr.y & 0xffffu));
        float x3 = b2f((u16)(xr.y >> 16));
        float4 wa = *(const float4*)(w0p + c);
        float4 wb = *(const float4*)(w0p + 1024 + c);
        float4 wc = *(const float4*)(w0p + 2048 + c);
        float4 wd = *(const float4*)(w0p + 3072 + c);
        a0 += x0*wa.x + x1*wa.y + x2*wa.z + x3*wa.w;
        a1 += x0*wb.x + x1*wb.y + x2*wb.z + x3*wb.w;
        a2 += x0*wc.x + x1*wc.y + x2*wc.z + x3*wc.w;
        a3 += x0*wd.x + x1*wd.y + x2*wd.z + x3*wd.w;
      }
      float s = (mat == 0) ? 0.25f : 1.f;
      float* qkm = &qk[mat*1088 + tok*17];
      qkm[grp] = a0*s; qkm[grp+4] = a1*s; qkm[grp+8] = a2*s; qkm[grp+12] = a3*s;
      __syncthreads();
    }
    float qv[16];
    const float* qrow = &qk[tok*17];
    #pragma unroll
    for (int d = 0; d < 16; ++d) qv[d] = qrow[d];
    float* sm = un;
    #pragma unroll 2
    for (int jj = 0; jj < 16; ++jj){
      int j = (grp<<4) + jj;
      const float* krow = &qk[1088 + j*17];
      float dacc = 0.f;
      #pragma unroll
      for (int d = 0; d < 16; ++d) dacc += qv[d]*krow[d];
      int rj = j >> 3, cj = j & 7;
      int idx = (ri - rj + 7)*15 + (ci - cj + 7);
      sm[tok*65 + j] = dacc + rpb[(idx<<4) + hd];
    }
    __syncthreads();
    if (t < 64){
      float* row = &sm[t*65];
      float mx = -1e30f;
      #pragma unroll 8
      for (int j = 0; j < 64; ++j) mx = fmaxf(mx, row[j]);
      float sum = 0.f;
      #pragma unroll 8
      for (int j = 0; j < 64; ++j){ float e_ = __expf(row[j]-mx); row[j] = e_; sum += e_; }
      float inv = 1.f / sum;
      #pragma unroll 8
      for (int j = 0; j < 64; ++j) row[j] *= inv;
    }
    __syncthreads();
    float o0=0.f,o1=0.f,o2=0.f,o3=0.f;
    const float* arow = &sm[tok*65];
    #pragma unroll 4
    for (int j = 0; j < 64; ++j){
      float a = arow[j];
      const float* vrow = &qk[2176 + j*17];
      o0 += a*vrow[grp]; o1 += a*vrow[grp+4]; o2 += a*vrow[grp+8]; o3 += a*vrow[grp+12];
    }
    int base = ((b*256 + (hd<<4) + grp)*256 + (h0 + ri))*256 + (w0 + ci);
    ATT[base]            = f2b(o0);
    ATT[base + 4*65536]  = f2b(o1);
    ATT[base + 8*65536]  = f2b(o2);
    ATT[base + 12*65536] = f2b(o3);
    __syncthreads();
  }
}

// ---------------------------------------------------------------------------
// K3: comb = avgpool_v(attn) + avgpool_h(attn) + local, in-place into LOCB.
// ---------------------------------------------------------------------------
__global__ __launch_bounds__(256) void k_comb(
    const u16* __restrict__ ATT, u16* __restrict__ LOCB){
  __shared__ float pt[39][256];
  int bi = blockIdx.x;
  int rb = bi & 7; int c = (bi>>3)&255; int b = bi>>11;
  int h0 = rb<<5;
  int t = threadIdx.x;
  const u16* P = ATT + (b*256 + c)*65536;
  for (int e = t; e < 9984; e += 256){
    int r = e >> 8; int cc = e & 255;
    int g = h0 - 3 + r;
    float v = 0.f;
    if ((unsigned)g < 256u) v = b2f(P[(g<<8) + cc]);
    else if (g == 256) v = b2f(P[(254<<8) + cc]);
    pt[r][cc] = v;
  }
  __syncthreads();
  int w = t;
  float colsum = 0.f;
  #pragma unroll
  for (int k = 0; k < 8; ++k) colsum += pt[k][w];
  u16* O = LOCB + (b*256 + c)*65536 + (h0<<8);
  for (int hr = 0; hr < 32; ++hr){
    const float* prow = pt[hr + 3];
    float s = 0.f;
    #pragma unroll
    for (int j = 0; j < 8; ++j){
      int cc = w - 3 + j;
      float v = 0.f;
      if ((unsigned)cc < 256u) v = prow[cc];
      else if (cc == 256) v = prow[254];
      s += v;
    }
    float res = (colsum + s)*0.125f + b2f(O[(hr<<8) + w]);
    O[(hr<<8) + w] = f2b(res);
    if (hr < 31) colsum += pt[hr+8][w] - pt[hr][w];
  }
}

// ---------------------------------------------------------------------------
// K4: 8x8 depthwise conv, reflect(0,1) pad + zero conv-pad 3 -> DWO (bf16)
// ---------------------------------------------------------------------------
__global__ __launch_bounds__(256) void k_dw(
    const u16* __restrict__ COMB, const float* __restrict__ wdw,
    u16* __restrict__ DWO){
  __shared__ float pt[39][264];
  __shared__ float wl[64];
  int bi = blockIdx.x;
  int rb = bi & 7; int c = (bi>>3)&255; int b = bi>>11;
  int h0 = rb<<5;
  int t = threadIdx.x;
  const u16* P = COMB + (b*256 + c)*65536;
  for (int e = t; e < 10296; e += 256){
    int r = e / 264; int cc = e - r*264;
    int g = h0 - 3 + r;
    int gc = cc - 3;
    int gr  = (g  == 256) ? 254 : g;
    int gcc = (gc == 256) ? 254 : gc;
    float v = 0.f;
    if (((unsigned)gr < 256u) && ((unsigned)gcc < 256u))
      v = b2f(P[(gr<<8) + gcc]);
    pt[r][cc] = v;
  }
  if (t < 64) wl[t] = wdw[(c<<6) + t];
  __syncthreads();
  int w = t;
  for (int hr = 0; hr < 32; ++hr){
    float acc = 0.f;
    #pragma unroll
    for (int i = 0; i < 8; ++i){
      const float* prow = &pt[hr + i][w];
      #pragma unroll
      for (int j = 0; j < 8; ++j)
        acc += wl[(i<<3) + j] * prow[j];
    }
    DWO[(b*256 + c)*65536 + ((h0+hr)<<8) + w] = f2b(acc);
  }
}

// ---------------------------------------------------------------------------
// K5: pointwise 1x1 (BNp folded) -> OUT fp32
// ---------------------------------------------------------------------------
__global__ __launch_bounds__(256) void k_pw(
    const u16* __restrict__ DW, const float* __restrict__ WPW,
    const float* __restrict__ BIASPW, float* __restrict__ OUT){
  __shared__ float wt[16][68];
  __shared__ float dt[16][65];
  int bi = blockIdx.x;
  int ot = bi & 3; int ptile = bi >> 2;
  int t = threadIdx.x;
  int p = t & 63, cg16 = (t>>6)<<4;
  int n0 = ptile << 6;
  int b = n0 >> 16; int pix0 = n0 & 65535;
  const u16* Dbase = DW + b*16777216 + pix0;
  float acc[16];
  #pragma unroll
  for (int i=0;i<16;++i) acc[i] = 0.f;
  for (int k0 = 0; k0 < 256; k0 += 16){
    for (int e = t; e < 1024; e += 256){
      int kk = e >> 6; int pp = e & 63;
      dt[kk][pp] = b2f(Dbase[(k0+kk)*65536 + pp]);
    }
    for (int e = t; e < 1024; e += 256){
      int oc_l = e >> 4; int k = e & 15;
      wt[k][oc_l] = WPW[((ot<<6) + oc_l)*256 + k0 + k];
    }
    __syncthreads();
    #pragma unroll
    for (int k = 0; k < 16; ++k){
      float dv = dt[k][p];
      const float* wr = &wt[k][cg16];
      float4 w0v = *(const float4*)(wr);
      float4 w1v = *(const float4*)(wr+4);
      float4 w2v = *(const float4*)(wr+8);
      float4 w3v = *(const float4*)(wr+12);
      acc[0]  += dv*w0v.x; acc[1]  += dv*w0v.y; acc[2]  += dv*w0v.z; acc[3]  += dv*w0v.w;
      acc[4]  += dv*w1v.x; acc[5]  += dv*w1v.y; acc[6]  += dv*w1v.z; acc[7]  += dv*w1v.w;
      acc[8]  += dv*w2v.x; acc[9]  += dv*w2v.y; acc[10] += dv*w2v.z; acc[11] += dv*w2v.w;
      acc[12] += dv*w3v.x; acc[13] += dv*w3v.y; acc[14] += dv*w3v.z; acc[15] += dv*w3v.w;
    }
    __syncthreads();
  }
  int oc0 = (ot<<6) + cg16;
  int ob = b*16777216 + pix0 + p;
  #pragma unroll
  for (int i=0;i<16;++i)
    OUT[ob + (oc0+i)*65536] = acc[i] + BIASPW[oc0+i];
}

// ---------------------------------------------------------------------------
extern "C" void kernel_launch(void* const* d_in, const int* in_sizes, int n_in,
                              void* d_out, int out_size, void* d_ws, size_t ws_size,
                              hipStream_t stream){
  const float* x    = (const float*)d_in[0];
  const float* y    = (const float*)d_in[1];
  const float* wqkv = (const float*)d_in[2];
  const float* wl1  = (const float*)d_in[3];
  const float* g1   = (const float*)d_in[4];
  const float* b1   = (const float*)d_in[5];
  const float* m1   = (const float*)d_in[6];
  const float* v1   = (const float*)d_in[7];
  const float* wl2  = (const float*)d_in[8];
  const float* g2   = (const float*)d_in[9];
  const float* b2   = (const float*)d_in[10];
  const float* m2   = (const float*)d_in[11];
  const float* v2   = (const float*)d_in[12];
  const float* wdw  = (const float*)d_in[13];
  const float* gp   = (const float*)d_in[14];
  const float* bp   = (const float*)d_in[15];
  const float* mp   = (const float*)d_in[16];
  const float* vp   = (const float*)d_in[17];
  const float* wpw  = (const float*)d_in[18];
  const float* rpb  = (const float*)d_in[19];

  float* BIASL  = (float*)d_ws;                    // 256 f32
  float* WPW    = BIASL + 256;                     // 65536 f32
  float* BIASPW = WPW + 65536;                     // 256 f32
  u16* W3B   = (u16*)(BIASPW + 256);               // 589824 bf16 (MFMA layout)
  u16* YTATT = W3B + 589824;                       // 33.5M bf16: YT, then ATT, then DWO
  u16* LOCB  = YTATT + 33554432;                   // 33.5M bf16: local -> comb in place
  float* OUT = (float*)d_out;

  k_prep_w3<<<2304, 256, 0, stream>>>(wl1, wl2, g1, b1, m1, v1, g2, b2, m2, v2, W3B, BIASL);
  k_prep_pw<<<1, 256, 0, stream>>>(wpw, gp, bp, mp, vp, WPW, BIASPW);
  k_prep_yT<<<512, 256, 0, stream>>>(y, YTATT);
  k_local<<<8192, 256, 0, stream>>>(YTATT, W3B, BIASL, LOCB);
  k_attn<<<2048, 256, 0, stream>>>(x, wqkv, rpb, YTATT);    // ATT overwrites dead YT
  k_comb<<<4096, 256, 0, stream>>>(YTATT, LOCB);
  k_dw<<<4096, 256, 0, stream>>>(LOCB, wdw, YTATT);         // DWO overwrites dead ATT
  k_pw<<<8192, 256, 0, stream>>>(YTATT, WPW, BIASPW, OUT);
}